// Round 7
// baseline (159.550 us; speedup 1.0000x reference)
//
#include <hip/hip_runtime.h>
#include <hip/hip_bf16.h>
#include <stdint.h>

typedef unsigned short u16;
typedef __attribute__((ext_vector_type(8))) unsigned short u16x8;
typedef __attribute__((ext_vector_type(4))) unsigned short u16x4;
typedef __attribute__((ext_vector_type(8))) __bf16 bf16x8;
typedef __attribute__((ext_vector_type(4))) float f32x4;

#define LOG2E 1.44269504088896340736f

#if defined(__has_builtin)
#if __has_builtin(__builtin_amdgcn_exp2f)
#define EXP2(x) __builtin_amdgcn_exp2f(x)
#endif
#endif
#ifndef EXP2
#define EXP2(x) exp2f(x)
#endif

// ---------- helpers ----------
__device__ __forceinline__ f32x4 mfma16(u16x8 a, u16x8 b, f32x4 c) {
  return __builtin_amdgcn_mfma_f32_16x16x32_bf16(
      __builtin_bit_cast(bf16x8, a), __builtin_bit_cast(bf16x8, b), c, 0, 0, 0);
}

__device__ __forceinline__ u16 f2bf(float f) {
  unsigned u = __builtin_bit_cast(unsigned, f);
  return (u16)((u + 0x7fffu + ((u >> 16) & 1u)) >> 16);
}

// pack two f32 -> two bf16 in one u32 (low = a, high = b), RNE
__device__ __forceinline__ unsigned cvtpk(float a, float b) {
  unsigned r;
  asm volatile("v_cvt_pk_bf16_f32 %0, %1, %2" : "=v"(r) : "v"(a), "v"(b));
  return r;
}

__device__ __forceinline__ void gload_lds16(const void* g, void* l) {
  __builtin_amdgcn_global_load_lds(
      (__attribute__((address_space(1))) void*)const_cast<void*>(g),
      (__attribute__((address_space(3))) void*)l, 16, 0, 0);
}

#define SWZ(row, colbyte) ((((row) * 128) + (colbyte)) ^ (((row) & 7) << 4))

// ---------- fp32 -> bf16 casts ----------
__global__ void cast_f32_bf16(const float* __restrict__ src, u16* __restrict__ dst, int n4) {
  int i = blockIdx.x * blockDim.x + threadIdx.x;
  if (i < n4) {
    f32x4 v = ((const f32x4*)src)[i];
    u16x4 o;
    o[0] = f2bf(v[0]); o[1] = f2bf(v[1]); o[2] = f2bf(v[2]); o[3] = f2bf(v[3]);
    ((u16x4*)dst)[i] = o;
  }
}

// three equal-size W matrices in one launch; per-matrix stride 1048576 ELEMENTS
__global__ void cast3_f32_bf16(const float* __restrict__ s0, const float* __restrict__ s1,
                               const float* __restrict__ s2, u16* __restrict__ dst) {
  const int seg = blockIdx.x >> 10;               // 0,1,2
  const int i = (blockIdx.x & 1023) * blockDim.x + threadIdx.x;  // < 262144
  const float* src = (seg == 0) ? s0 : ((seg == 1) ? s1 : s2);
  f32x4 v = ((const f32x4*)src)[i];
  u16x4 o;
  o[0] = f2bf(v[0]); o[1] = f2bf(v[1]); o[2] = f2bf(v[2]); o[3] = f2bf(v[3]);
  ((u16x4*)(dst + (size_t)seg * 1048576))[i] = o;
}

// ---------- fused QKV GEMM (double-buffered, pipelined, XCD-swizzled) ----------
// Q pre-scaled by 0.125*log2e so attention exps are raw v_exp_f32 (2^x).
__global__ __launch_bounds__(256) void gemm_qkv(
    const u16* __restrict__ A, const u16* __restrict__ Bm,
    const float* __restrict__ bq, const float* __restrict__ bk, const float* __restrict__ bv,
    u16* __restrict__ Qb, u16* __restrict__ Kb, u16* __restrict__ VTb) {
  __shared__ __align__(16) u16 Asm[2][128 * 32];  // 16 KB
  __shared__ __align__(16) u16 Bsm[2][128 * 32];  // 16 KB
  const int tid = threadIdx.x;
  const int wave = tid >> 6, lane = tid & 63;
  const int lq = lane & 15, lg = lane >> 4;
  const int wr = wave >> 1, wc = wave & 1;
  // XCD-bijective swizzle: 768 blocks = 8 XCDs x 96; each XCD gets 4 m-rows x 24 n
  const int lin = blockIdx.y * 24 + blockIdx.x;
  const int wg = (lin & 7) * 96 + (lin >> 3);
  const int m0 = (wg / 24) * 128, n0 = (wg % 24) * 128;

  f32x4 zero = {0.f, 0.f, 0.f, 0.f};
  f32x4 acc[4][4];
#pragma unroll
  for (int mi = 0; mi < 4; ++mi)
#pragma unroll
    for (int ni = 0; ni < 4; ++ni) acc[mi][ni] = zero;

  auto stage = [&](int kt, int buf) {
    const int k0 = kt * 32;
#pragma unroll
    for (int c = 0; c < 2; ++c) {
      const int idx = wave * 2 + c;
      const u16* ga = A + (size_t)(m0 + idx * 16 + (lane >> 2)) * 1024 + k0 + (lane & 3) * 8;
      gload_lds16(ga, (char*)&Asm[buf][0] + idx * 1024);
      const u16* gb = Bm + (size_t)(n0 + idx * 16 + (lane >> 2)) * 1024 + k0 + (lane & 3) * 8;
      gload_lds16(gb, (char*)&Bsm[buf][0] + idx * 1024);
    }
  };

  stage(0, 0);
  __syncthreads();
  for (int kt = 0; kt < 32; ++kt) {
    const int cur = kt & 1;
    if (kt + 1 < 32) stage(kt + 1, cur ^ 1);

    u16x8 af[4], bfr[4];
#pragma unroll
    for (int mi = 0; mi < 4; ++mi)
      af[mi] = *(const u16x8*)&Asm[cur][(wr * 64 + mi * 16 + lq) * 32 + lg * 8];
#pragma unroll
    for (int ni = 0; ni < 4; ++ni)
      bfr[ni] = *(const u16x8*)&Bsm[cur][(wc * 64 + ni * 16 + lq) * 32 + lg * 8];
#pragma unroll
    for (int mi = 0; mi < 4; ++mi)
#pragma unroll
      for (int ni = 0; ni < 4; ++ni)
        acc[mi][ni] = mfma16(af[mi], bfr[ni], acc[mi][ni]);
    __syncthreads();
  }

  const int which = n0 >> 10;  // 0=Q, 1=K, 2=V (uniform per block)
  const float* bias = (which == 0) ? bq : ((which == 1) ? bk : bv);
  const float scl = (which == 0) ? (0.125f * LOG2E) : 1.0f;
#pragma unroll
  for (int mi = 0; mi < 4; ++mi) {
    const int m = m0 + wr * 64 + mi * 16 + lg * 4;
    const int bb = m >> 11;
    const int s = m & 2047;
#pragma unroll
    for (int ni = 0; ni < 4; ++ni) {
      const int n = n0 + wc * 64 + ni * 16 + lq;
      const int d = n & 1023;
      const int h = d >> 6, dh = d & 63;
      const float bi = bias[d];
#pragma unroll
      for (int r = 0; r < 4; ++r) {
        float v = (acc[mi][ni][r] + bi) * scl;
        if (which == 2)
          VTb[(((size_t)bb * 16 + h) * 64 + dh) * 2048 + (size_t)(s + r)] = f2bf(v);
        else {
          u16* dst = (which == 0) ? Qb : Kb;
          dst[(((size_t)bb * 16 + h) * 2048 + (size_t)(s + r)) * 64 + dh] = f2bf(v);
        }
      }
    }
  }
}

// ---------- attention: single pass, m=0 softmax, unnormalized PV ----------
// 256 thr = 4 waves, wave owns 32 q (q-tile 128); grid 512 = 2 blocks/CU.
// Swapped QK^T -> l lane-local; P bf16 (unnormalized) -> PV; epilogue * 1/l.
__global__ __launch_bounds__(256) void attn_main(
    const u16* __restrict__ Qb, const u16* __restrict__ Kb, const u16* __restrict__ VTb,
    const float* __restrict__ maskg, float* __restrict__ out_ctx, float* __restrict__ winv) {
  __shared__ __align__(16) u16 Kl[2][4096];   // 16 KB
  __shared__ __align__(16) u16 VTl[2][4096];  // 16 KB
  __shared__ __align__(16) u16 Pl[4][2048];   // 16 KB: per-wave 32q x 64k bf16

  const int tid = threadIdx.x;
  const int w = tid >> 6, lane = tid & 63;
  const int lq = lane & 15, lg = lane >> 4;
  // XCD swizzle: 512 blocks, 64/XCD -> bh 0..3 on XCD0, etc.
  const int bid = (blockIdx.x & 7) * 64 + (blockIdx.x >> 3);
  const int qt = bid & 15, bh = bid >> 4;
  const int b = bh >> 4, h = bh & 15;
  const int qw = qt * 128 + w * 32;  // wave's first q row

  // Q frags: group lo = rows qw+lq, hi = rows qw+16+lq
  const u16* qp0 = Qb + ((size_t)bh * 2048 + qw + lq) * 64 + lg * 8;
  const u16* qp1 = qp0 + 16 * 64;
  const u16x8 qa00 = *(const u16x8*)qp0, qa01 = *(const u16x8*)(qp0 + 32);
  const u16x8 qa10 = *(const u16x8*)qp1, qa11 = *(const u16x8*)(qp1 + 32);

  const char* Kbase = (const char*)(Kb + (size_t)bh * 2048 * 64);
  const char* VTbase = (const char*)(VTb + (size_t)bh * 64 * 2048);
  const float* mbase = maskg + b * 2048;

  // staging: 512 x 16B chunks per 8KB tile, 2 per thread; pre-swizzled source
  const int r0 = w * 8 + (lane >> 3);                   // rows r0 and r0+32
  const int s0c = ((lane & 7) * 16) ^ ((r0 & 7) << 4);  // same swizzle both rows

  auto stageK = [&](int kt, int buf) {
    const char* src = Kbase + (size_t)(kt * 64) * 128;
    gload_lds16(src + (size_t)r0 * 128 + s0c, (char*)&Kl[buf][0] + w * 1024);
    gload_lds16(src + (size_t)(r0 + 32) * 128 + s0c, (char*)&Kl[buf][0] + 4096 + w * 1024);
  };
  auto stageVT = [&](int kt, int buf) {
    const char* src = VTbase + (size_t)kt * 128;
    gload_lds16(src + (size_t)r0 * 4096 + s0c, (char*)&VTl[buf][0] + w * 1024);
    gload_lds16(src + (size_t)(r0 + 32) * 4096 + s0c, (char*)&VTl[buf][0] + 4096 + w * 1024);
  };

  f32x4 acc[2][4];
  {
    f32x4 zero = {0.f, 0.f, 0.f, 0.f};
#pragma unroll
    for (int g = 0; g < 2; ++g)
#pragma unroll
      for (int ni = 0; ni < 4; ++ni) acc[g][ni] = zero;
  }
  float l_lo = 0.f, l_hi = 0.f;
  char* Pw = (char*)&Pl[w][0];

  stageK(0, 0);
  stageVT(0, 0);
  __syncthreads();
  for (int kt = 0; kt < 32; ++kt) {
    const int cur = kt & 1;
    if (kt + 1 < 32) { stageK(kt + 1, cur ^ 1); stageVT(kt + 1, cur ^ 1); }
    const char* Kt = (const char*)&Kl[cur][0];
    const char* Vt = (const char*)&VTl[cur][0];

#pragma unroll
    for (int chunk = 0; chunk < 4; ++chunk) {
      const int krow = chunk * 16 + lq;
      const u16x8 ka0 = *(const u16x8*)(Kt + SWZ(krow, lg * 16));
      const u16x8 ka1 = *(const u16x8*)(Kt + SWZ(krow, 64 + lg * 16));
      f32x4 z = {0.f, 0.f, 0.f, 0.f};
      f32x4 slo = mfma16(ka0, qa00, z);   // D[k=chunk*16+lg*4+r][q=lq]
      slo = mfma16(ka1, qa01, slo);
      f32x4 shi = mfma16(ka0, qa10, z);
      shi = mfma16(ka1, qa11, shi);
      const f32x4 mv = *(const f32x4*)(mbase + kt * 64 + chunk * 16 + lg * 4);
      float pl[4], ph[4];
#pragma unroll
      for (int r = 0; r < 4; ++r) {
        pl[r] = EXP2(fmaf(mv[r], LOG2E, slo[r]));  // unnormalized
        ph[r] = EXP2(fmaf(mv[r], LOG2E, shi[r]));
        l_lo += pl[r];
        l_hi += ph[r];
      }
      // P write: rows q-sub (lq / 16+lq), 4 consecutive k -> one b64 write each
      uint2 wlo, whi;
      wlo.x = cvtpk(pl[0], pl[1]); wlo.y = cvtpk(pl[2], pl[3]);
      whi.x = cvtpk(ph[0], ph[1]); whi.y = cvtpk(ph[2], ph[3]);
      *(uint2*)(Pw + SWZ(lq, chunk * 32 + lg * 8)) = wlo;
      *(uint2*)(Pw + SWZ(16 + lq, chunk * 32 + lg * 8)) = whi;
    }

    // PV: ctx[q][dh] += P[q][k] * VT[dh][k]^T
#pragma unroll
    for (int kc = 0; kc < 2; ++kc) {
      const u16x8 pa0 = *(const u16x8*)(Pw + SWZ(lq, kc * 64 + lg * 16));
      const u16x8 pa1 = *(const u16x8*)(Pw + SWZ(16 + lq, kc * 64 + lg * 16));
#pragma unroll
      for (int ni = 0; ni < 4; ++ni) {
        const u16x8 vb = *(const u16x8*)(Vt + SWZ(ni * 16 + lq, kc * 64 + lg * 16));
        acc[0][ni] = mfma16(pa0, vb, acc[0][ni]);
        acc[1][ni] = mfma16(pa1, vb, acc[1][ni]);
      }
    }
    __syncthreads();
  }

  // reduce l over the 4 lg-groups (distinct k each)
  l_lo += __shfl_xor(l_lo, 16); l_lo += __shfl_xor(l_lo, 32);
  l_hi += __shfl_xor(l_hi, 16); l_hi += __shfl_xor(l_hi, 32);
  const float il_lo = 1.0f / l_lo;
  const float il_hi = 1.0f / l_hi;
  if (lg == 0) {
    winv[bh * 2048 + qw + lq] = il_lo;
    winv[bh * 2048 + qw + 16 + lq] = il_hi;
  }
  // redistribute 1/l to PV output rows (q-sub = lg*4+r)
  f32x4 il4[2];
#pragma unroll
  for (int r = 0; r < 4; ++r) {
    il4[0][r] = __shfl(il_lo, lg * 4 + r);
    il4[1][r] = __shfl(il_hi, lg * 4 + r);
  }
#pragma unroll
  for (int g = 0; g < 2; ++g) {
    const int qrow = b * 2048 + qw + g * 16 + lg * 4;
#pragma unroll
    for (int ni = 0; ni < 4; ++ni) {
      const int dh = h * 64 + ni * 16 + lq;
#pragma unroll
      for (int r = 0; r < 4; ++r)
        out_ctx[(size_t)(qrow + r) * 1024 + dh] = acc[g][ni][r] * il4[g][r];
    }
  }
}

// ---------- colsum: c_k = sum_q exp2(s + mask*L) * winv_q ----------
// 256 thr = 4 waves; wave owns 32 k (2 reg K-frag groups); block 128 k.
// Grid 512 = 2 blocks/CU; Q streamed through LDS (double-buffered).
__global__ __launch_bounds__(256) void colsum_kernel(
    const u16* __restrict__ Qb, const u16* __restrict__ Kb,
    const float* __restrict__ maskg, const float* __restrict__ winv,
    float* __restrict__ out_cs) {
  __shared__ __align__(16) u16 Ql[2][4096];  // 16 KB

  const int tid = threadIdx.x;
  const int w = tid >> 6, lane = tid & 63;
  const int lq = lane & 15, lg = lane >> 4;
  // XCD swizzle aligned with attn: bh = bid>>4 -> 4 bh per XCD
  const int bid = (blockIdx.x & 7) * 64 + (blockIdx.x >> 3);
  const int ktile = bid & 15, bh = bid >> 4;
  const int b = bh >> 4;
  const int kbase = ktile * 128 + w * 32;

  // two reg-resident K fragment groups: k = kbase+lq and kbase+16+lq
  const u16* kp0 = Kb + ((size_t)bh * 2048 + kbase + lq) * 64 + lg * 8;
  const u16* kp1 = kp0 + 16 * 64;
  const u16x8 kb00 = *(const u16x8*)kp0, kb01 = *(const u16x8*)(kp0 + 32);
  const u16x8 kb10 = *(const u16x8*)kp1, kb11 = *(const u16x8*)(kp1 + 32);
  const float mvl0 = maskg[b * 2048 + kbase + lq] * LOG2E;
  const float mvl1 = maskg[b * 2048 + kbase + 16 + lq] * LOG2E;
  const float* wbase = winv + bh * 2048;
  const char* Qbase = (const char*)(Qb + (size_t)bh * 2048 * 64);

  // staging: 512 chunks per 64-row Q tile, 2 per thread (rows r0 / r0+32)
  const int r0 = tid >> 3;
  const int scol = ((tid & 7) * 16) ^ ((r0 & 7) << 4);
  auto stageQ = [&](int qt, int buf) {
    const char* src = Qbase + (size_t)(qt * 64) * 128;
    char* d = (char*)&Ql[buf][0] + w * 1024;
    gload_lds16(src + (size_t)r0 * 128 + scol, d);
    gload_lds16(src + (size_t)(r0 + 32) * 128 + scol, d + 4096);
  };

  float c0 = 0.f, c1 = 0.f;
  stageQ(0, 0);
  __syncthreads();
  for (int qt = 0; qt < 32; ++qt) {
    const int cur = qt & 1;
    if (qt + 1 < 32) stageQ(qt + 1, cur ^ 1);
    const char* Qt = (const char*)&Ql[cur][0];
#pragma unroll
    for (int chunk = 0; chunk < 4; ++chunk) {
      const u16x8 qf0 = *(const u16x8*)(Qt + SWZ(chunk * 16 + lq, lg * 16));
      const u16x8 qf1 = *(const u16x8*)(Qt + SWZ(chunk * 16 + lq, 64 + lg * 16));
      f32x4 z = {0.f, 0.f, 0.f, 0.f};
      f32x4 s0 = mfma16(qf0, kb00, z);   // D[q=qt*64+chunk*16+lg*4+r][k=kbase+lq]
      s0 = mfma16(qf1, kb01, s0);
      f32x4 s1 = mfma16(qf0, kb10, z);   // k = kbase+16+lq
      s1 = mfma16(qf1, kb11, s1);
      const f32x4 wv = *(const f32x4*)(wbase + qt * 64 + chunk * 16 + lg * 4);
#pragma unroll
      for (int r = 0; r < 4; ++r) {
        c0 += EXP2(s0[r] + mvl0) * wv[r];
        c1 += EXP2(s1[r] + mvl1) * wv[r];
      }
    }
    __syncthreads();
  }
  c0 += __shfl_xor(c0, 16); c0 += __shfl_xor(c0, 32);
  c1 += __shfl_xor(c1, 16); c1 += __shfl_xor(c1, 32);
  if (lg == 0) {
    atomicAdd(&out_cs[b * 2048 + kbase + lq], c0);
    atomicAdd(&out_cs[b * 2048 + kbase + 16 + lq], c1);
  }
}

// ---------- launch ----------
extern "C" void kernel_launch(void* const* d_in, const int* in_sizes, int n_in,
                              void* d_out, int out_size, void* d_ws, size_t ws_size,
                              hipStream_t stream) {
  (void)in_sizes; (void)n_in; (void)out_size; (void)ws_size;
  const float* X    = (const float*)d_in[0];
  const float* mask = (const float*)d_in[1];
  const float* Wq   = (const float*)d_in[2];
  const float* bq   = (const float*)d_in[3];
  const float* Wk   = (const float*)d_in[4];
  const float* bk   = (const float*)d_in[5];
  const float* Wv   = (const float*)d_in[6];
  const float* bv   = (const float*)d_in[7];
  float* out = (float*)d_out;

  char* ws = (char*)d_ws;
  u16* Xb   = (u16*)(ws);                  // 8 MiB (dead after gemm)
  u16* Wcat = (u16*)(ws + 8388608);        // 6 MiB
  u16* Qb   = (u16*)(ws + 14680064);       // 8 MiB
  u16* Kb   = (u16*)(ws + 23068672);       // 8 MiB
  u16* VTb  = (u16*)(ws + 31457280);       // 8 MiB (transposed V)
  float* winv = (float*)(ws + 39845888);   // 256 KiB

  cast_f32_bf16<<<4096, 256, 0, stream>>>(X, Xb, 1048576);
  cast3_f32_bf16<<<3072, 256, 0, stream>>>(Wq, Wk, Wv, Wcat);

  hipMemsetAsync(out + 4194304, 0, 4096 * sizeof(float), stream);

  gemm_qkv<<<dim3(24, 32), 256, 0, stream>>>(Xb, Wcat, bq, bk, bv, Qb, Kb, VTb);

  attn_main<<<512, 256, 0, stream>>>(Qb, Kb, VTb, mask, out, winv);
  colsum_kernel<<<512, 256, 0, stream>>>(Qb, Kb, mask, winv, out + 4194304);
}

// Round 8
// 142.100 us; speedup vs baseline: 1.1228x; 1.1228x over previous
//
#include <hip/hip_runtime.h>
#include <hip/hip_bf16.h>
#include <stdint.h>

typedef unsigned short u16;
typedef __attribute__((ext_vector_type(8))) unsigned short u16x8;
typedef __attribute__((ext_vector_type(4))) unsigned short u16x4;
typedef __attribute__((ext_vector_type(8))) __bf16 bf16x8;
typedef __attribute__((ext_vector_type(4))) float f32x4;

#define LOG2E 1.44269504088896340736f

#if defined(__has_builtin)
#if __has_builtin(__builtin_amdgcn_exp2f)
#define EXP2(x) __builtin_amdgcn_exp2f(x)
#endif
#endif
#ifndef EXP2
#define EXP2(x) exp2f(x)
#endif

// ---------- helpers ----------
__device__ __forceinline__ f32x4 mfma16(u16x8 a, u16x8 b, f32x4 c) {
  return __builtin_amdgcn_mfma_f32_16x16x32_bf16(
      __builtin_bit_cast(bf16x8, a), __builtin_bit_cast(bf16x8, b), c, 0, 0, 0);
}

__device__ __forceinline__ u16 f2bf(float f) {
  unsigned u = __builtin_bit_cast(unsigned, f);
  return (u16)((u + 0x7fffu + ((u >> 16) & 1u)) >> 16);
}

__device__ __forceinline__ unsigned cvtpk(float a, float b) {
  unsigned r;
  asm volatile("v_cvt_pk_bf16_f32 %0, %1, %2" : "=v"(r) : "v"(a), "v"(b));
  return r;
}

__device__ __forceinline__ void gload_lds16(const void* g, void* l) {
  __builtin_amdgcn_global_load_lds(
      (__attribute__((address_space(1))) void*)const_cast<void*>(g),
      (__attribute__((address_space(3))) void*)l, 16, 0, 0);
}

// counted vmcnt wait (T4): keep newer prefetches in flight across the barrier
template<int N> __device__ __forceinline__ void vmwait() {
  asm volatile("s_waitcnt vmcnt(%0)" :: "n"(N) : "memory");
  __builtin_amdgcn_sched_barrier(0);
}

#define SWZ(row, colbyte) ((((row) * 128) + (colbyte)) ^ (((row) & 7) << 4))

// ---------- fp32 -> bf16 casts ----------
__global__ void cast_f32_bf16(const float* __restrict__ src, u16* __restrict__ dst, int n4) {
  int i = blockIdx.x * blockDim.x + threadIdx.x;
  if (i < n4) {
    f32x4 v = ((const f32x4*)src)[i];
    u16x4 o;
    o[0] = f2bf(v[0]); o[1] = f2bf(v[1]); o[2] = f2bf(v[2]); o[3] = f2bf(v[3]);
    ((u16x4*)dst)[i] = o;
  }
}

// three equal-size W matrices in one launch; per-matrix stride 1048576 ELEMENTS
__global__ void cast3_f32_bf16(const float* __restrict__ s0, const float* __restrict__ s1,
                               const float* __restrict__ s2, u16* __restrict__ dst) {
  const int seg = blockIdx.x >> 10;
  const int i = (blockIdx.x & 1023) * blockDim.x + threadIdx.x;
  const float* src = (seg == 0) ? s0 : ((seg == 1) ? s1 : s2);
  f32x4 v = ((const f32x4*)src)[i];
  u16x4 o;
  o[0] = f2bf(v[0]); o[1] = f2bf(v[1]); o[2] = f2bf(v[2]); o[3] = f2bf(v[3]);
  ((u16x4*)(dst + (size_t)seg * 1048576))[i] = o;
}

// ---------- fused QKV GEMM (3-buf, depth-2 prefetch, counted vmcnt) ----------
// Q pre-scaled by 0.125*log2e so attention exps are raw v_exp_f32 (2^x).
__global__ __launch_bounds__(256) void gemm_qkv(
    const u16* __restrict__ A, const u16* __restrict__ Bm,
    const float* __restrict__ bq, const float* __restrict__ bk, const float* __restrict__ bv,
    u16* __restrict__ Qb, u16* __restrict__ Kb, u16* __restrict__ VTb) {
  __shared__ __align__(16) u16 Asm[3][4096];  // 24 KB
  __shared__ __align__(16) u16 Bsm[3][4096];  // 24 KB
  const int tid = threadIdx.x;
  const int wave = tid >> 6, lane = tid & 63;
  const int lq = lane & 15, lg = lane >> 4;
  const int wr = wave >> 1, wc = wave & 1;
  // XCD-bijective swizzle: 768 blocks = 8 XCDs x 96
  const int lin = blockIdx.y * 24 + blockIdx.x;
  const int wg = (lin & 7) * 96 + (lin >> 3);
  const int m0 = (wg / 24) * 128, n0 = (wg % 24) * 128;

  f32x4 zero = {0.f, 0.f, 0.f, 0.f};
  f32x4 acc[4][4];
#pragma unroll
  for (int mi = 0; mi < 4; ++mi)
#pragma unroll
    for (int ni = 0; ni < 4; ++ni) acc[mi][ni] = zero;

  auto stage = [&](int kt, int buf) {   // 4 loads/thread
    const int k0 = kt * 32;
#pragma unroll
    for (int c = 0; c < 2; ++c) {
      const int idx = wave * 2 + c;
      const u16* ga = A + (size_t)(m0 + idx * 16 + (lane >> 2)) * 1024 + k0 + (lane & 3) * 8;
      gload_lds16(ga, (char*)&Asm[buf][0] + idx * 1024);
      const u16* gb = Bm + (size_t)(n0 + idx * 16 + (lane >> 2)) * 1024 + k0 + (lane & 3) * 8;
      gload_lds16(gb, (char*)&Bsm[buf][0] + idx * 1024);
    }
  };

  stage(0, 0);
  stage(1, 1);
  for (int kt = 0; kt < 32; ++kt) {
    if (kt < 31) vmwait<4>(); else vmwait<0>();   // drain stage(kt) only
    __builtin_amdgcn_s_barrier();
    if (kt + 2 < 32) stage(kt + 2, (kt + 2) % 3);
    const int cur = kt % 3;

    __builtin_amdgcn_s_setprio(1);
    u16x8 af[4], bfr[4];
#pragma unroll
    for (int mi = 0; mi < 4; ++mi)
      af[mi] = *(const u16x8*)&Asm[cur][(wr * 64 + mi * 16 + lq) * 32 + lg * 8];
#pragma unroll
    for (int ni = 0; ni < 4; ++ni)
      bfr[ni] = *(const u16x8*)&Bsm[cur][(wc * 64 + ni * 16 + lq) * 32 + lg * 8];
#pragma unroll
    for (int mi = 0; mi < 4; ++mi)
#pragma unroll
      for (int ni = 0; ni < 4; ++ni)
        acc[mi][ni] = mfma16(af[mi], bfr[ni], acc[mi][ni]);
    __builtin_amdgcn_s_setprio(0);
  }

  const int which = n0 >> 10;  // 0=Q, 1=K, 2=V (uniform per block)
  const float* bias = (which == 0) ? bq : ((which == 1) ? bk : bv);
  const float scl = (which == 0) ? (0.125f * LOG2E) : 1.0f;
#pragma unroll
  for (int mi = 0; mi < 4; ++mi) {
    const int m = m0 + wr * 64 + mi * 16 + lg * 4;
    const int bb = m >> 11;
    const int s = m & 2047;
#pragma unroll
    for (int ni = 0; ni < 4; ++ni) {
      const int n = n0 + wc * 64 + ni * 16 + lq;
      const int d = n & 1023;
      const int h = d >> 6, dh = d & 63;
      const float bi = bias[d];
#pragma unroll
      for (int r = 0; r < 4; ++r) {
        float v = (acc[mi][ni][r] + bi) * scl;
        if (which == 2)
          VTb[(((size_t)bb * 16 + h) * 64 + dh) * 2048 + (size_t)(s + r)] = f2bf(v);
        else {
          u16* dst = (which == 0) ? Qb : Kb;
          dst[(((size_t)bb * 16 + h) * 2048 + (size_t)(s + r)) * 64 + dh] = f2bf(v);
        }
      }
    }
  }
}

// ---------- attention: single pass, m=0 softmax, unnormalized PV ----------
// 512 thr = 8 waves, 16q/wave (q-tile 128); grid 512 = 2 blocks/CU.
// 3-buf K/VT, depth-2 prefetch, counted vmcnt, raw barrier (T3+T4), setprio (T5).
__global__ __launch_bounds__(512) void attn_main(
    const u16* __restrict__ Qb, const u16* __restrict__ Kb, const u16* __restrict__ VTb,
    const float* __restrict__ maskg, float* __restrict__ out_ctx, float* __restrict__ winv) {
  __shared__ __align__(16) u16 Kl[3][4096];   // 24 KB
  __shared__ __align__(16) u16 VTl[3][4096];  // 24 KB
  __shared__ __align__(16) u16 Pl[8][1024];   // 16 KB: per-wave 16q x 64k bf16

  const int tid = threadIdx.x;
  const int w = tid >> 6, lane = tid & 63;
  const int lq = lane & 15, lg = lane >> 4;
  // XCD swizzle: 512 blocks, 64/XCD -> 4 consecutive bh per XCD
  const int bid = (blockIdx.x & 7) * 64 + (blockIdx.x >> 3);
  const int qt = bid & 15, bh = bid >> 4;
  const int b = bh >> 4, h = bh & 15;
  const int qw = qt * 128 + w * 16;  // wave's first q row

  // Q frags: lane holds Q[qw+lq][dh 8lg.. , +32]
  const u16* qp = Qb + ((size_t)bh * 2048 + qw + lq) * 64 + lg * 8;
  const u16x8 qa0 = *(const u16x8*)qp;
  const u16x8 qa1 = *(const u16x8*)(qp + 32);

  const char* Kbase = (const char*)(Kb + (size_t)bh * 2048 * 64);
  const char* VTbase = (const char*)(VTb + (size_t)bh * 64 * 2048);
  const float* mbase = maskg + b * 2048;

  // staging: 512 x 16B chunks per 8KB tile, 1 per thread; pre-swizzled source
  const int srow = tid >> 3;
  const int scol = ((tid & 7) * 16) ^ ((srow & 7) << 4);

  auto stageK = [&](int kt, int buf) {   // 1 load/thread
    gload_lds16(Kbase + (size_t)(kt * 64 + srow) * 128 + scol, (char*)&Kl[buf][0] + w * 1024);
  };
  auto stageVT = [&](int kt, int buf) {  // 1 load/thread
    gload_lds16(VTbase + (size_t)srow * 4096 + (size_t)kt * 128 + scol, (char*)&VTl[buf][0] + w * 1024);
  };

  f32x4 acc[4];
  {
    f32x4 zero = {0.f, 0.f, 0.f, 0.f};
#pragma unroll
    for (int ni = 0; ni < 4; ++ni) acc[ni] = zero;
  }
  float l_l = 0.f;
  char* Pw = (char*)&Pl[w][0];

  stageK(0, 0); stageVT(0, 0);
  stageK(1, 1); stageVT(1, 1);
  for (int kt = 0; kt < 32; ++kt) {
    if (kt < 31) vmwait<2>(); else vmwait<0>();   // drain stage(kt); keep stage(kt+1) in flight
    __builtin_amdgcn_s_barrier();
    if (kt + 2 < 32) {
      const int nb = (kt + 2) % 3;
      stageK(kt + 2, nb);
      stageVT(kt + 2, nb);
    }
    const int cur = kt % 3;
    const char* Kt = (const char*)&Kl[cur][0];
    const char* Vt = (const char*)&VTl[cur][0];

    __builtin_amdgcn_s_setprio(1);
#pragma unroll
    for (int chunk = 0; chunk < 4; ++chunk) {
      const int krow = chunk * 16 + lq;
      const u16x8 ka0 = *(const u16x8*)(Kt + SWZ(krow, lg * 16));
      const u16x8 ka1 = *(const u16x8*)(Kt + SWZ(krow, 64 + lg * 16));
      f32x4 z = {0.f, 0.f, 0.f, 0.f};
      f32x4 s = mfma16(ka0, qa0, z);   // D[k=chunk*16+lg*4+r][q=lq]
      s = mfma16(ka1, qa1, s);
      const f32x4 mv = *(const f32x4*)(mbase + kt * 64 + chunk * 16 + lg * 4);
      float p[4];
#pragma unroll
      for (int r = 0; r < 4; ++r) {
        p[r] = EXP2(fmaf(mv[r], LOG2E, s[r]));  // unnormalized
        l_l += p[r];
      }
      uint2 wp;
      wp.x = cvtpk(p[0], p[1]); wp.y = cvtpk(p[2], p[3]);
      *(uint2*)(Pw + SWZ(lq, chunk * 32 + lg * 8)) = wp;
    }

    // PV: ctx[q][dh] += P[q][k] * VT[dh][k]^T
#pragma unroll
    for (int kc = 0; kc < 2; ++kc) {
      const u16x8 pa = *(const u16x8*)(Pw + SWZ(lq, kc * 64 + lg * 16));
#pragma unroll
      for (int ni = 0; ni < 4; ++ni) {
        const u16x8 vb = *(const u16x8*)(Vt + SWZ(ni * 16 + lq, kc * 64 + lg * 16));
        acc[ni] = mfma16(pa, vb, acc[ni]);
      }
    }
    __builtin_amdgcn_s_setprio(0);
  }

  // reduce l over the 4 lg-groups (distinct k each)
  l_l += __shfl_xor(l_l, 16);
  l_l += __shfl_xor(l_l, 32);
  const float il = 1.0f / l_l;
  if (lg == 0) winv[bh * 2048 + qw + lq] = il;

  // redistribute 1/l to PV output rows (q-sub = lg*4+r)
  f32x4 il4;
#pragma unroll
  for (int r = 0; r < 4; ++r) il4[r] = __shfl(il, lg * 4 + r);

  const int qrow = b * 2048 + qw + lg * 4;
#pragma unroll
  for (int ni = 0; ni < 4; ++ni) {
    const int dh = h * 64 + ni * 16 + lq;
#pragma unroll
    for (int r = 0; r < 4; ++r)
      out_ctx[(size_t)(qrow + r) * 1024 + dh] = acc[ni][r] * il4[r];
  }
}

// ---------- colsum: c_k = sum_q exp2(s + mask*L) * winv_q ----------
// 256 thr = 4 waves; wave owns 32 k (2 reg K-frag groups); block 128 k.
// Grid 512; 3-buf Q staging with counted vmcnt.
__global__ __launch_bounds__(256) void colsum_kernel(
    const u16* __restrict__ Qb, const u16* __restrict__ Kb,
    const float* __restrict__ maskg, const float* __restrict__ winv,
    float* __restrict__ out_cs) {
  __shared__ __align__(16) u16 Ql[3][4096];  // 24 KB

  const int tid = threadIdx.x;
  const int w = tid >> 6, lane = tid & 63;
  const int lq = lane & 15, lg = lane >> 4;
  const int bid = (blockIdx.x & 7) * 64 + (blockIdx.x >> 3);
  const int ktile = bid & 15, bh = bid >> 4;
  const int b = bh >> 4;
  const int kbase = ktile * 128 + w * 32;

  const u16* kp0 = Kb + ((size_t)bh * 2048 + kbase + lq) * 64 + lg * 8;
  const u16* kp1 = kp0 + 16 * 64;
  const u16x8 kb00 = *(const u16x8*)kp0, kb01 = *(const u16x8*)(kp0 + 32);
  const u16x8 kb10 = *(const u16x8*)kp1, kb11 = *(const u16x8*)(kp1 + 32);
  const float mvl0 = maskg[b * 2048 + kbase + lq] * LOG2E;
  const float mvl1 = maskg[b * 2048 + kbase + 16 + lq] * LOG2E;
  const float* wbase = winv + bh * 2048;
  const char* Qbase = (const char*)(Qb + (size_t)bh * 2048 * 64);

  const int r0 = tid >> 3;
  const int scol = ((tid & 7) * 16) ^ ((r0 & 7) << 4);
  auto stageQ = [&](int qt, int buf) {   // 2 loads/thread
    const char* src = Qbase + (size_t)(qt * 64) * 128;
    char* d = (char*)&Ql[buf][0] + w * 1024;
    gload_lds16(src + (size_t)r0 * 128 + scol, d);
    gload_lds16(src + (size_t)(r0 + 32) * 128 + scol, d + 4096);
  };

  float c0 = 0.f, c1 = 0.f;
  stageQ(0, 0);
  stageQ(1, 1);
  for (int qt = 0; qt < 32; ++qt) {
    if (qt < 31) vmwait<2>(); else vmwait<0>();
    __builtin_amdgcn_s_barrier();
    if (qt + 2 < 32) stageQ(qt + 2, (qt + 2) % 3);
    const char* Qt = (const char*)&Ql[qt % 3][0];
#pragma unroll
    for (int chunk = 0; chunk < 4; ++chunk) {
      const u16x8 qf0 = *(const u16x8*)(Qt + SWZ(chunk * 16 + lq, lg * 16));
      const u16x8 qf1 = *(const u16x8*)(Qt + SWZ(chunk * 16 + lq, 64 + lg * 16));
      f32x4 z = {0.f, 0.f, 0.f, 0.f};
      f32x4 s0 = mfma16(qf0, kb00, z);   // D[q=qt*64+chunk*16+lg*4+r][k=kbase+lq]
      s0 = mfma16(qf1, kb01, s0);
      f32x4 s1 = mfma16(qf0, kb10, z);   // k = kbase+16+lq
      s1 = mfma16(qf1, kb11, s1);
      const f32x4 wv = *(const f32x4*)(wbase + qt * 64 + chunk * 16 + lg * 4);
#pragma unroll
      for (int r = 0; r < 4; ++r) {
        c0 += EXP2(s0[r] + mvl0) * wv[r];
        c1 += EXP2(s1[r] + mvl1) * wv[r];
      }
    }
  }
  c0 += __shfl_xor(c0, 16); c0 += __shfl_xor(c0, 32);
  c1 += __shfl_xor(c1, 16); c1 += __shfl_xor(c1, 32);
  if (lg == 0) {
    atomicAdd(&out_cs[b * 2048 + kbase + lq], c0);
    atomicAdd(&out_cs[b * 2048 + kbase + 16 + lq], c1);
  }
}

// ---------- launch ----------
extern "C" void kernel_launch(void* const* d_in, const int* in_sizes, int n_in,
                              void* d_out, int out_size, void* d_ws, size_t ws_size,
                              hipStream_t stream) {
  (void)in_sizes; (void)n_in; (void)out_size; (void)ws_size;
  const float* X    = (const float*)d_in[0];
  const float* mask = (const float*)d_in[1];
  const float* Wq   = (const float*)d_in[2];
  const float* bq   = (const float*)d_in[3];
  const float* Wk   = (const float*)d_in[4];
  const float* bk   = (const float*)d_in[5];
  const float* Wv   = (const float*)d_in[6];
  const float* bv   = (const float*)d_in[7];
  float* out = (float*)d_out;

  char* ws = (char*)d_ws;
  u16* Xb   = (u16*)(ws);                  // 8 MiB (dead after gemm)
  u16* Wcat = (u16*)(ws + 8388608);        // 6 MiB
  u16* Qb   = (u16*)(ws + 14680064);       // 8 MiB
  u16* Kb   = (u16*)(ws + 23068672);       // 8 MiB
  u16* VTb  = (u16*)(ws + 31457280);       // 8 MiB (transposed V)
  float* winv = (float*)(ws + 39845888);   // 256 KiB

  cast_f32_bf16<<<4096, 256, 0, stream>>>(X, Xb, 1048576);
  cast3_f32_bf16<<<3072, 256, 0, stream>>>(Wq, Wk, Wv, Wcat);

  hipMemsetAsync(out + 4194304, 0, 4096 * sizeof(float), stream);

  gemm_qkv<<<dim3(24, 32), 256, 0, stream>>>(Xb, Wcat, bq, bk, bv, Qb, Kb, VTb);

  attn_main<<<512, 512, 0, stream>>>(Qb, Kb, VTb, mask, out, winv);
  colsum_kernel<<<512, 256, 0, stream>>>(Qb, Kb, mask, winv, out + 4194304);
}